// Round 4
// baseline (4330.931 us; speedup 1.0000x reference)
//
#include <hip/hip_runtime.h>

// MPM P2G scatter: quadratic B-spline, 3x3x3 stencil.
// Outputs (concatenated in d_out, fp32):
//   grids [T,G,G,G]        -> d_out[0 .. T*G^3)
//   gdef  [T,G,G,G,3]      -> d_out[T*G^3 .. 4*T*G^3)

constexpr int   G      = 128;
constexpr float MINN   = -15.0f;
constexpr float EXTENT = 40.0f;

__global__ void __launch_bounds__(256)
p2g_kernel(const float* __restrict__ xs, const float* __restrict__ def,
           float* __restrict__ grids, float* __restrict__ gdef, int N)
{
    const int p = blockIdx.x * blockDim.x + threadIdx.x;
    const int t = blockIdx.y;
    if (p >= N) return;

    const long i = (long)t * N + p;
    const float x  = xs[i * 3 + 0];
    const float y  = xs[i * 3 + 1];
    const float z  = xs[i * 3 + 2];
    const float dx = def[i * 3 + 0];
    const float dy = def[i * 3 + 1];
    const float dz = def[i * 3 + 2];

    const float scale = (float)G / EXTENT;
    const float Xp = (x - MINN) * scale;
    const float Yp = (y - MINN) * scale;
    const float Zp = (z - MINN) * scale;

    int bx = (int)floorf(Xp - 0.5f);
    int by = (int)floorf(Yp - 0.5f);
    int bz = (int)floorf(Zp - 0.5f);

    // fx from the UNclamped base (matches the reference; clip affects idx only)
    const float fx = Xp - (float)bx;
    const float fy = Yp - (float)by;
    const float fz = Zp - (float)bz;

    float wx[3], wy[3], wz[3];
    wx[0] = 0.5f * (1.5f - fx) * (1.5f - fx);
    wx[1] = 0.75f - (fx - 1.0f) * (fx - 1.0f);
    wx[2] = 0.5f * (fx - 0.5f) * (fx - 0.5f);
    wy[0] = 0.5f * (1.5f - fy) * (1.5f - fy);
    wy[1] = 0.75f - (fy - 1.0f) * (fy - 1.0f);
    wy[2] = 0.5f * (fy - 0.5f) * (fy - 0.5f);
    wz[0] = 0.5f * (1.5f - fz) * (1.5f - fz);
    wz[1] = 0.75f - (fz - 1.0f) * (fz - 1.0f);
    wz[2] = 0.5f * (fz - 0.5f) * (fz - 0.5f);

    bx = min(max(bx, 0), G - 3);
    by = min(max(by, 0), G - 3);
    bz = min(max(bz, 0), G - 3);

    const long tbase = (long)t * G * G * G;
    #pragma unroll
    for (int ii = 0; ii < 3; ++ii) {
        const float wxi  = wx[ii];
        const long  xoff = tbase + (long)(bx + ii) * (G * G);
        #pragma unroll
        for (int jj = 0; jj < 3; ++jj) {
            const float wij  = wxi * wy[jj];
            const long  yoff = xoff + (long)(by + jj) * G;
            #pragma unroll
            for (int kk = 0; kk < 3; ++kk) {
                const float w   = wij * wz[kk];
                const long  idx = yoff + (bz + kk);
                atomicAdd(&grids[idx], w);                 // P_MASS = 1.0
                atomicAdd(&gdef[idx * 3 + 0], w * dx);
                atomicAdd(&gdef[idx * 3 + 1], w * dy);
                atomicAdd(&gdef[idx * 3 + 2], w * dz);
            }
        }
    }
}

extern "C" void kernel_launch(void* const* d_in, const int* in_sizes, int n_in,
                              void* d_out, int out_size, void* d_ws, size_t ws_size,
                              hipStream_t stream)
{
    const float* xs  = (const float*)d_in[0];
    const float* def = (const float*)d_in[1];
    float* out = (float*)d_out;

    const long Gcells = (long)G * G * G;            // 2,097,152
    const int  T = (int)(out_size / (Gcells * 4));  // grids + 3*gdef per timestep
    const int  N = in_sizes[0] / (3 * T);

    float* grids = out;
    float* gdef  = out + (long)T * Gcells;

    hipMemsetAsync(d_out, 0, (size_t)out_size * sizeof(float), stream);

    dim3 block(256);
    dim3 grid((N + 255) / 256, T);
    p2g_kernel<<<grid, block, 0, stream>>>(xs, def, grids, gdef, N);
}

// Round 5
// 631.252 us; speedup vs baseline: 6.8609x; 6.8609x over previous
//
#include <hip/hip_runtime.h>

// MPM P2G scatter: quadratic B-spline, 3x3x3 stencil.
// Strategy: counting-sort particles into 8^3-cell bins per timestep, then one
// block per 8^3 output tile accumulates its cells in LDS (ds_add_f32) and
// writes the tile with plain coalesced stores. Zero global atomics in the hot
// path; every output cell written exactly once (no d_out memset needed).
//
// Outputs (concatenated in d_out, fp32):
//   grids [T,G,G,G]        -> d_out[0 .. T*G^3)
//   gdef  [T,G,G,G,3]      -> d_out[T*G^3 .. 4*T*G^3)

constexpr int   G      = 128;
constexpr float MINN   = -15.0f;
constexpr float EXTENT = 40.0f;
constexpr int   NB     = 16;              // bins per axis (8 cells per bin)
constexpr int   NBINS  = NB * NB * NB;    // 4096 bins per timestep

__device__ __forceinline__ int3 base_cell(float x, float y, float z,
                                          float& fx, float& fy, float& fz)
{
    const float scale = (float)G / EXTENT;
    const float Xp = (x - MINN) * scale;
    const float Yp = (y - MINN) * scale;
    const float Zp = (z - MINN) * scale;
    int bx = (int)floorf(Xp - 0.5f);
    int by = (int)floorf(Yp - 0.5f);
    int bz = (int)floorf(Zp - 0.5f);
    // fx from the UNclamped base (matches reference); clamp affects indices only
    fx = Xp - (float)bx; fy = Yp - (float)by; fz = Zp - (float)bz;
    bx = min(max(bx, 0), G - 3);
    by = min(max(by, 0), G - 3);
    bz = min(max(bz, 0), G - 3);
    return make_int3(bx, by, bz);
}

__device__ __forceinline__ int bin_of(const int3& b)
{
    return ((b.x >> 3) * NB + (b.y >> 3)) * NB + (b.z >> 3);
}

// ---- K1: per-(t,bin) particle histogram --------------------------------------
__global__ void __launch_bounds__(256)
hist_kernel(const float* __restrict__ xs, int* __restrict__ hist, int N)
{
    const int p = blockIdx.x * blockDim.x + threadIdx.x;
    const int t = blockIdx.y;
    if (p >= N) return;
    const long i = (long)t * N + p;
    float fx, fy, fz;
    int3 b = base_cell(xs[i*3], xs[i*3+1], xs[i*3+2], fx, fy, fz);
    atomicAdd(&hist[t * NBINS + bin_of(b)], 1);
}

// ---- K2: exclusive scan of 4096 bins per timestep (one block per t) ----------
__global__ void __launch_bounds__(256)
scan_kernel(const int* __restrict__ hist, int* __restrict__ bin_start,
            int* __restrict__ cursor)
{
    const int t = blockIdx.x, tid = threadIdx.x;   // 256 threads, 16 bins each
    __shared__ int part[256];
    int local[16], s = 0;
    const int base = t * NBINS + tid * 16;
    #pragma unroll
    for (int i = 0; i < 16; ++i) { local[i] = s; s += hist[base + i]; }
    part[tid] = s;
    __syncthreads();
    const int own = s;
    for (int d = 1; d < 256; d <<= 1) {
        int v = (tid >= d) ? part[tid - d] : 0;
        __syncthreads();
        part[tid] += v;
        __syncthreads();
    }
    const int excl = part[tid] - own;              // exclusive prefix of this chunk
    #pragma unroll
    for (int i = 0; i < 16; ++i) {
        const int v = excl + local[i];
        bin_start[base + i] = v;
        cursor[base + i]    = v;
    }
}

// ---- K3: scatter particles into bin-sorted order -----------------------------
__global__ void __launch_bounds__(256)
scatter_kernel(const float* __restrict__ xs, const float* __restrict__ def,
               int* __restrict__ cursor,
               float4* __restrict__ sA, float2* __restrict__ sB, int N)
{
    const int p = blockIdx.x * blockDim.x + threadIdx.x;
    const int t = blockIdx.y;
    if (p >= N) return;
    const long i = (long)t * N + p;
    const float x = xs[i*3], y = xs[i*3+1], z = xs[i*3+2];
    float fx, fy, fz;
    int3 b = base_cell(x, y, z, fx, fy, fz);
    const int slot = atomicAdd(&cursor[t * NBINS + bin_of(b)], 1);
    const long o = (long)t * N + slot;
    sA[o] = make_float4(x, y, z, def[i*3]);
    sB[o] = make_float2(def[i*3+1], def[i*3+2]);
}

// ---- K4: tile-owned P2G, LDS accumulate, plain store -------------------------
__global__ void __launch_bounds__(128)
p2g_tiled(const float4* __restrict__ sA, const float2* __restrict__ sB,
          const int* __restrict__ bin_start, const int* __restrict__ hist,
          float* __restrict__ grids, float* __restrict__ gdef, int N)
{
    const int tile = blockIdx.x, t = blockIdx.y, tid = threadIdx.x;
    const int tx = tile >> 8, ty = (tile >> 4) & 15, tz = tile & 15;
    const int c0x = tx * 8, c0y = ty * 8, c0z = tz * 8;

    __shared__ float sm[512 * 4];                  // [cell][mass,dx,dy,dz] = 8 KB
    for (int l = tid; l < 2048; l += 128) sm[l] = 0.0f;
    __syncthreads();

    // contributions reach tile from its own bin and the -1 neighbor bins only
    for (int dxb = -1; dxb <= 0; ++dxb) {
        const int bbx = tx + dxb; if (bbx < 0) continue;
        for (int dyb = -1; dyb <= 0; ++dyb) {
            const int bby = ty + dyb; if (bby < 0) continue;
            for (int dzb = -1; dzb <= 0; ++dzb) {
                const int bbz = tz + dzb; if (bbz < 0) continue;
                const int bin   = t * NBINS + (bbx * NB + bby) * NB + bbz;
                const int start = bin_start[bin];
                const int cnt   = hist[bin];
                const long src  = (long)t * N + start;
                for (int j = tid; j < cnt; j += 128) {
                    const float4 a = sA[src + j];
                    float fx, fy, fz;
                    int3 b = base_cell(a.x, a.y, a.z, fx, fy, fz);
                    if (b.x + 2 < c0x || b.x > c0x + 7 ||
                        b.y + 2 < c0y || b.y > c0y + 7 ||
                        b.z + 2 < c0z || b.z > c0z + 7) continue;
                    const float2 d2 = sB[src + j];

                    float wx[3], wy[3], wz[3];
                    wx[0] = 0.5f*(1.5f-fx)*(1.5f-fx); wx[1] = 0.75f-(fx-1.f)*(fx-1.f); wx[2] = 0.5f*(fx-0.5f)*(fx-0.5f);
                    wy[0] = 0.5f*(1.5f-fy)*(1.5f-fy); wy[1] = 0.75f-(fy-1.f)*(fy-1.f); wy[2] = 0.5f*(fy-0.5f)*(fy-0.5f);
                    wz[0] = 0.5f*(1.5f-fz)*(1.5f-fz); wz[1] = 0.75f-(fz-1.f)*(fz-1.f); wz[2] = 0.5f*(fz-0.5f)*(fz-0.5f);

                    const int ilo = max(b.x, c0x) - b.x, ihi = min(b.x + 2, c0x + 7) - b.x;
                    const int jlo = max(b.y, c0y) - b.y, jhi = min(b.y + 2, c0y + 7) - b.y;
                    const int klo = max(b.z, c0z) - b.z, khi = min(b.z + 2, c0z + 7) - b.z;
                    for (int oi = ilo; oi <= ihi; ++oi) {
                        const int lx = b.x + oi - c0x;
                        for (int oj = jlo; oj <= jhi; ++oj) {
                            const int ly = b.y + oj - c0y;
                            const float wxy = wx[oi] * wy[oj];
                            for (int ok = klo; ok <= khi; ++ok) {
                                const int lz = b.z + ok - c0z;
                                const float w = wxy * wz[ok];
                                const int cell = (((lx << 3) + ly) << 3) + lz;
                                atomicAdd(&sm[cell*4 + 0], w);          // P_MASS = 1
                                atomicAdd(&sm[cell*4 + 1], w * a.w);
                                atomicAdd(&sm[cell*4 + 2], w * d2.x);
                                atomicAdd(&sm[cell*4 + 3], w * d2.y);
                            }
                        }
                    }
                }
            }
        }
    }
    __syncthreads();

    // flush: every global cell owned by exactly one tile -> plain stores
    const long tbase = (long)t * G * G * G;
    for (int cell = tid; cell < 512; cell += 128) {
        const int lx = cell >> 6, ly = (cell >> 3) & 7, lz = cell & 7;
        const long gidx = tbase + (long)(c0x + lx) * (G * G) + (c0y + ly) * G + (c0z + lz);
        grids[gidx]        = sm[cell*4 + 0];
        gdef[gidx*3 + 0]   = sm[cell*4 + 1];
        gdef[gidx*3 + 1]   = sm[cell*4 + 2];
        gdef[gidx*3 + 2]   = sm[cell*4 + 3];
    }
}

// ---- fallback: direct global-atomic scatter (verified round-4 baseline) ------
__global__ void __launch_bounds__(256)
p2g_direct(const float* __restrict__ xs, const float* __restrict__ def,
           float* __restrict__ grids, float* __restrict__ gdef, int N)
{
    const int p = blockIdx.x * blockDim.x + threadIdx.x;
    const int t = blockIdx.y;
    if (p >= N) return;
    const long i = (long)t * N + p;
    const float dx = def[i*3], dy = def[i*3+1], dz = def[i*3+2];
    float fx, fy, fz;
    int3 b = base_cell(xs[i*3], xs[i*3+1], xs[i*3+2], fx, fy, fz);
    float wx[3], wy[3], wz[3];
    wx[0] = 0.5f*(1.5f-fx)*(1.5f-fx); wx[1] = 0.75f-(fx-1.f)*(fx-1.f); wx[2] = 0.5f*(fx-0.5f)*(fx-0.5f);
    wy[0] = 0.5f*(1.5f-fy)*(1.5f-fy); wy[1] = 0.75f-(fy-1.f)*(fy-1.f); wy[2] = 0.5f*(fy-0.5f)*(fy-0.5f);
    wz[0] = 0.5f*(1.5f-fz)*(1.5f-fz); wz[1] = 0.75f-(fz-1.f)*(fz-1.f); wz[2] = 0.5f*(fz-0.5f)*(fz-0.5f);
    const long tbase = (long)t * G * G * G;
    #pragma unroll
    for (int ii = 0; ii < 3; ++ii) {
        const long xoff = tbase + (long)(b.x + ii) * (G * G);
        #pragma unroll
        for (int jj = 0; jj < 3; ++jj) {
            const float wij = wx[ii] * wy[jj];
            const long yoff = xoff + (long)(b.y + jj) * G;
            #pragma unroll
            for (int kk = 0; kk < 3; ++kk) {
                const float w = wij * wz[kk];
                const long idx = yoff + (b.z + kk);
                atomicAdd(&grids[idx], w);
                atomicAdd(&gdef[idx*3+0], w * dx);
                atomicAdd(&gdef[idx*3+1], w * dy);
                atomicAdd(&gdef[idx*3+2], w * dz);
            }
        }
    }
}

extern "C" void kernel_launch(void* const* d_in, const int* in_sizes, int n_in,
                              void* d_out, int out_size, void* d_ws, size_t ws_size,
                              hipStream_t stream)
{
    const float* xs  = (const float*)d_in[0];
    const float* def = (const float*)d_in[1];
    float* out = (float*)d_out;

    const long Gcells = (long)G * G * G;
    const int  T = (int)(out_size / (Gcells * 4));
    const int  N = in_sizes[0] / (3 * T);

    float* grids = out;
    float* gdef  = out + (long)T * Gcells;

    // workspace layout
    const size_t szA   = (size_t)T * N * sizeof(float4);   // 12.8 MB
    const size_t szB   = (size_t)T * N * sizeof(float2);   //  6.4 MB
    const size_t szInt = (size_t)T * NBINS * sizeof(int);  //  128 KB each
    const size_t need  = szA + szB + 3 * szInt;

    if (ws_size < need) {
        // not enough scratch: verified direct-atomic path
        hipMemsetAsync(d_out, 0, (size_t)out_size * sizeof(float), stream);
        dim3 grid((N + 255) / 256, T);
        p2g_direct<<<grid, dim3(256), 0, stream>>>(xs, def, grids, gdef, N);
        return;
    }

    char* ws = (char*)d_ws;
    float4* sA       = (float4*)ws;                    ws += szA;
    float2* sB       = (float2*)ws;                    ws += szB;
    int*    hist     = (int*)ws;                       ws += szInt;
    int*    cursor   = (int*)ws;                       ws += szInt;
    int*    binstart = (int*)ws;

    hipMemsetAsync(hist, 0, szInt, stream);

    dim3 pgrid((N + 255) / 256, T);
    hist_kernel   <<<pgrid, dim3(256), 0, stream>>>(xs, hist, N);
    scan_kernel   <<<dim3(T), dim3(256), 0, stream>>>(hist, binstart, cursor);
    scatter_kernel<<<pgrid, dim3(256), 0, stream>>>(xs, def, cursor, sA, sB, N);
    p2g_tiled     <<<dim3(NBINS, T), dim3(128), 0, stream>>>(sA, sB, binstart, hist,
                                                             grids, gdef, N);
}

// Round 6
// 495.088 us; speedup vs baseline: 8.7478x; 1.2750x over previous
//
#include <hip/hip_runtime.h>

// MPM P2G, quadratic B-spline, 3x3x3 stencil.
// Full-sort + gather strategy:
//   1) counting-sort particles by clamped base CELL (per timestep)
//   2) one thread per output cell gathers its <=27-source-cell window:
//      9 (x,y) rows, z-window contiguous in sorted order -> no atomics,
//      no redundant reads, coalesced stores, each cell written once.
// Fallbacks: round-5 bin-tile scatter (ws >= ~20MB), then direct atomics.
//
// Outputs (concatenated in d_out, fp32):
//   grids [T,G,G,G]   -> d_out[0 .. T*G^3)
//   gdef  [T,G,G,G,3] -> d_out[T*G^3 .. 4*T*G^3)

constexpr int   G      = 128;
constexpr int   CELLS  = G * G * G;       // 2,097,152
constexpr float MINN   = -15.0f;
constexpr float EXTENT = 40.0f;
constexpr int   NB     = 16;              // fallback path: 8-cell bins
constexpr int   NBINS  = NB * NB * NB;

__device__ __forceinline__ int3 base_cell(float x, float y, float z,
                                          float& fx, float& fy, float& fz)
{
    const float scale = (float)G / EXTENT;
    const float Xp = (x - MINN) * scale;
    const float Yp = (y - MINN) * scale;
    const float Zp = (z - MINN) * scale;
    int bx = (int)floorf(Xp - 0.5f);
    int by = (int)floorf(Yp - 0.5f);
    int bz = (int)floorf(Zp - 0.5f);
    // fx from the UNclamped base (matches reference); clamp affects indices only
    fx = Xp - (float)bx; fy = Yp - (float)by; fz = Zp - (float)bz;
    bx = min(max(bx, 0), G - 3);
    by = min(max(by, 0), G - 3);
    bz = min(max(bz, 0), G - 3);
    return make_int3(bx, by, bz);
}

__device__ __forceinline__ float wsel(float f, int d)
{
    const float r0 = 1.5f - f, r1 = f - 1.0f, r2 = f - 0.5f;
    const float w0 = 0.5f * r0 * r0;
    const float w1 = 0.75f - r1 * r1;
    const float w2 = 0.5f * r2 * r2;
    return d == 0 ? w0 : (d == 1 ? w1 : w2);
}

// ======================= full-sort path =======================

// K1: per-cell histogram
__global__ void __launch_bounds__(256)
cell_hist(const float* __restrict__ xs, int* __restrict__ arr, int N)
{
    const int p = blockIdx.x * blockDim.x + threadIdx.x;
    const int t = blockIdx.y;
    if (p >= N) return;
    const long i = (long)t * N + p;
    float fx, fy, fz;
    int3 b = base_cell(xs[i*3], xs[i*3+1], xs[i*3+2], fx, fy, fz);
    const int key = (b.x << 14) + (b.y << 7) + b.z;
    atomicAdd(&arr[(long)t * CELLS + key], 1);
}

// K2a: per-4096-chunk exclusive scan (in place) + chunk totals
__global__ void __launch_bounds__(256)
scan1(int* __restrict__ arr, int* __restrict__ sums)
{
    const int t = blockIdx.y, tid = threadIdx.x;
    int* a = arr + (long)t * CELLS + (long)blockIdx.x * 4096 + tid * 16;
    int local[16], s = 0;
    #pragma unroll
    for (int i = 0; i < 16; ++i) { const int v = a[i]; local[i] = s; s += v; }
    __shared__ int part[256];
    part[tid] = s;
    __syncthreads();
    const int own = s;
    for (int d = 1; d < 256; d <<= 1) {
        int v = (tid >= d) ? part[tid - d] : 0;
        __syncthreads();
        part[tid] += v;
        __syncthreads();
    }
    const int excl = part[tid] - own;
    #pragma unroll
    for (int i = 0; i < 16; ++i) a[i] = excl + local[i];
    if (tid == 255) sums[t * 512 + blockIdx.x] = part[255];
}

// K2b: exclusive scan of the 512 chunk totals per timestep
__global__ void __launch_bounds__(256)
scan2(int* __restrict__ sums)
{
    const int t = blockIdx.x, tid = threadIdx.x;
    int* s = sums + t * 512 + tid * 2;
    const int v0 = s[0], v1 = s[1];
    const int tot = v0 + v1;
    __shared__ int part[256];
    part[tid] = tot;
    __syncthreads();
    for (int d = 1; d < 256; d <<= 1) {
        int v = (tid >= d) ? part[tid - d] : 0;
        __syncthreads();
        part[tid] += v;
        __syncthreads();
    }
    const int excl = part[tid] - tot;
    s[0] = excl; s[1] = excl + v0;
}

// K2c: add chunk offsets (block fully inside one 4096-chunk; uniform add)
__global__ void __launch_bounds__(256)
scan3(int* __restrict__ arr, const int* __restrict__ sums)
{
    const int t = blockIdx.y;
    const int add = sums[t * 512 + (blockIdx.x >> 2)];
    int4* p = (int4*)(arr + (long)t * CELLS + (long)blockIdx.x * 1024 + threadIdx.x * 4);
    int4 v = *p;
    v.x += add; v.y += add; v.z += add; v.w += add;
    *p = v;
}

// K3: scatter particles into cell-sorted order (arr becomes END offsets)
__global__ void __launch_bounds__(256)
scatter_cells(const float* __restrict__ xs, const float* __restrict__ def,
              int* __restrict__ arr,
              float4* __restrict__ sA, float2* __restrict__ sB, int N)
{
    const int p = blockIdx.x * blockDim.x + threadIdx.x;
    const int t = blockIdx.y;
    if (p >= N) return;
    const long i = (long)t * N + p;
    const float x = xs[i*3], y = xs[i*3+1], z = xs[i*3+2];
    float fx, fy, fz;
    int3 b = base_cell(x, y, z, fx, fy, fz);
    const int key = (b.x << 14) + (b.y << 7) + b.z;
    const int slot = atomicAdd(&arr[(long)t * CELLS + key], 1);
    const long o = (long)t * N + slot;
    sA[o] = make_float4(x, y, z, def[i*3]);
    sB[o] = make_float2(def[i*3+1], def[i*3+2]);
}

// K4: gather — one thread per output cell, no atomics, write-once
__global__ void __launch_bounds__(256)
gather_cells(const float4* __restrict__ sA, const float2* __restrict__ sB,
             const int* __restrict__ arr,
             float* __restrict__ grids, float* __restrict__ gdef, int N)
{
    const int cell = blockIdx.x * 256 + threadIdx.x;
    const int t = blockIdx.y;
    const int cz = cell & (G - 1);
    const int cy = (cell >> 7) & (G - 1);
    const int cx = cell >> 14;

    const int* a = arr + (long)t * CELLS;
    const long pbase = (long)t * N;

    float m = 0.f, vx = 0.f, vy = 0.f, vz = 0.f;

    // contributing bases: x in [cx-2,cx], y in [cy-2,cy], clamped to [0,G-3];
    // z-window [cz-2,cz] is contiguous in the sort; cells z=126,127 are empty
    // (bases clamp to <=125) so the unclamped z-window is safe.
    const int xlo = max(cx - 2, 0), xhi = min(cx, G - 3);
    const int ylo = max(cy - 2, 0), yhi = min(cy, G - 3);
    for (int x = xlo; x <= xhi; ++x) {
        for (int y = ylo; y <= yhi; ++y) {
            const int row = (x << 14) + (y << 7);
            const int f0 = row + cz - 2;
            const int f1 = row + cz;
            const int s0 = (f0 <= 0) ? 0 : a[f0 - 1];   // arr[c-1] = start(c)
            const int s1 = a[f1];                        // arr[c]   = end(c)
            for (int s = s0; s < s1; ++s) {
                const float4 A = sA[pbase + s];
                const float2 B = sB[pbase + s];
                float fx, fy, fz;
                int3 b = base_cell(A.x, A.y, A.z, fx, fy, fz);
                const float w = wsel(fx, cx - b.x) * wsel(fy, cy - b.y) * wsel(fz, cz - b.z);
                m  += w;            // P_MASS = 1
                vx += w * A.w;
                vy += w * B.x;
                vz += w * B.y;
            }
        }
    }

    const long gidx = (long)t * CELLS + cell;
    grids[gidx]      = m;
    gdef[gidx*3 + 0] = vx;
    gdef[gidx*3 + 1] = vy;
    gdef[gidx*3 + 2] = vz;
}

// ======================= fallback: round-5 bin-tile path =======================

__device__ __forceinline__ int bin_of(const int3& b)
{
    return ((b.x >> 3) * NB + (b.y >> 3)) * NB + (b.z >> 3);
}

__global__ void __launch_bounds__(256)
hist_kernel(const float* __restrict__ xs, int* __restrict__ hist, int N)
{
    const int p = blockIdx.x * blockDim.x + threadIdx.x;
    const int t = blockIdx.y;
    if (p >= N) return;
    const long i = (long)t * N + p;
    float fx, fy, fz;
    int3 b = base_cell(xs[i*3], xs[i*3+1], xs[i*3+2], fx, fy, fz);
    atomicAdd(&hist[t * NBINS + bin_of(b)], 1);
}

__global__ void __launch_bounds__(256)
scan_kernel(const int* __restrict__ hist, int* __restrict__ bin_start,
            int* __restrict__ cursor)
{
    const int t = blockIdx.x, tid = threadIdx.x;
    __shared__ int part[256];
    int local[16], s = 0;
    const int base = t * NBINS + tid * 16;
    #pragma unroll
    for (int i = 0; i < 16; ++i) { local[i] = s; s += hist[base + i]; }
    part[tid] = s;
    __syncthreads();
    const int own = s;
    for (int d = 1; d < 256; d <<= 1) {
        int v = (tid >= d) ? part[tid - d] : 0;
        __syncthreads();
        part[tid] += v;
        __syncthreads();
    }
    const int excl = part[tid] - own;
    #pragma unroll
    for (int i = 0; i < 16; ++i) {
        const int v = excl + local[i];
        bin_start[base + i] = v;
        cursor[base + i]    = v;
    }
}

__global__ void __launch_bounds__(256)
scatter_kernel(const float* __restrict__ xs, const float* __restrict__ def,
               int* __restrict__ cursor,
               float4* __restrict__ sA, float2* __restrict__ sB, int N)
{
    const int p = blockIdx.x * blockDim.x + threadIdx.x;
    const int t = blockIdx.y;
    if (p >= N) return;
    const long i = (long)t * N + p;
    const float x = xs[i*3], y = xs[i*3+1], z = xs[i*3+2];
    float fx, fy, fz;
    int3 b = base_cell(x, y, z, fx, fy, fz);
    const int slot = atomicAdd(&cursor[t * NBINS + bin_of(b)], 1);
    const long o = (long)t * N + slot;
    sA[o] = make_float4(x, y, z, def[i*3]);
    sB[o] = make_float2(def[i*3+1], def[i*3+2]);
}

__global__ void __launch_bounds__(128)
p2g_tiled(const float4* __restrict__ sA, const float2* __restrict__ sB,
          const int* __restrict__ bin_start, const int* __restrict__ hist,
          float* __restrict__ grids, float* __restrict__ gdef, int N)
{
    const int tile = blockIdx.x, t = blockIdx.y, tid = threadIdx.x;
    const int tx = tile >> 8, ty = (tile >> 4) & 15, tz = tile & 15;
    const int c0x = tx * 8, c0y = ty * 8, c0z = tz * 8;

    __shared__ float sm[512 * 4];
    for (int l = tid; l < 2048; l += 128) sm[l] = 0.0f;
    __syncthreads();

    for (int dxb = -1; dxb <= 0; ++dxb) {
        const int bbx = tx + dxb; if (bbx < 0) continue;
        for (int dyb = -1; dyb <= 0; ++dyb) {
            const int bby = ty + dyb; if (bby < 0) continue;
            for (int dzb = -1; dzb <= 0; ++dzb) {
                const int bbz = tz + dzb; if (bbz < 0) continue;
                const int bin   = t * NBINS + (bbx * NB + bby) * NB + bbz;
                const int start = bin_start[bin];
                const int cnt   = hist[bin];
                const long src  = (long)t * N + start;
                for (int j = tid; j < cnt; j += 128) {
                    const float4 a = sA[src + j];
                    float fx, fy, fz;
                    int3 b = base_cell(a.x, a.y, a.z, fx, fy, fz);
                    if (b.x + 2 < c0x || b.x > c0x + 7 ||
                        b.y + 2 < c0y || b.y > c0y + 7 ||
                        b.z + 2 < c0z || b.z > c0z + 7) continue;
                    const float2 d2 = sB[src + j];

                    float wx[3], wy[3], wz[3];
                    wx[0] = 0.5f*(1.5f-fx)*(1.5f-fx); wx[1] = 0.75f-(fx-1.f)*(fx-1.f); wx[2] = 0.5f*(fx-0.5f)*(fx-0.5f);
                    wy[0] = 0.5f*(1.5f-fy)*(1.5f-fy); wy[1] = 0.75f-(fy-1.f)*(fy-1.f); wy[2] = 0.5f*(fy-0.5f)*(fy-0.5f);
                    wz[0] = 0.5f*(1.5f-fz)*(1.5f-fz); wz[1] = 0.75f-(fz-1.f)*(fz-1.f); wz[2] = 0.5f*(fz-0.5f)*(fz-0.5f);

                    const int ilo = max(b.x, c0x) - b.x, ihi = min(b.x + 2, c0x + 7) - b.x;
                    const int jlo = max(b.y, c0y) - b.y, jhi = min(b.y + 2, c0y + 7) - b.y;
                    const int klo = max(b.z, c0z) - b.z, khi = min(b.z + 2, c0z + 7) - b.z;
                    for (int oi = ilo; oi <= ihi; ++oi) {
                        const int lx = b.x + oi - c0x;
                        for (int oj = jlo; oj <= jhi; ++oj) {
                            const int ly = b.y + oj - c0y;
                            const float wxy = wx[oi] * wy[oj];
                            for (int ok = klo; ok <= khi; ++ok) {
                                const int lz = b.z + ok - c0z;
                                const float w = wxy * wz[ok];
                                const int cell = (((lx << 3) + ly) << 3) + lz;
                                atomicAdd(&sm[cell*4 + 0], w);
                                atomicAdd(&sm[cell*4 + 1], w * a.w);
                                atomicAdd(&sm[cell*4 + 2], w * d2.x);
                                atomicAdd(&sm[cell*4 + 3], w * d2.y);
                            }
                        }
                    }
                }
            }
        }
    }
    __syncthreads();

    const long tbase = (long)t * G * G * G;
    for (int cell = tid; cell < 512; cell += 128) {
        const int lx = cell >> 6, ly = (cell >> 3) & 7, lz = cell & 7;
        const long gidx = tbase + (long)(c0x + lx) * (G * G) + (c0y + ly) * G + (c0z + lz);
        grids[gidx]      = sm[cell*4 + 0];
        gdef[gidx*3 + 0] = sm[cell*4 + 1];
        gdef[gidx*3 + 1] = sm[cell*4 + 2];
        gdef[gidx*3 + 2] = sm[cell*4 + 3];
    }
}

// last-resort fallback: direct global atomics
__global__ void __launch_bounds__(256)
p2g_direct(const float* __restrict__ xs, const float* __restrict__ def,
           float* __restrict__ grids, float* __restrict__ gdef, int N)
{
    const int p = blockIdx.x * blockDim.x + threadIdx.x;
    const int t = blockIdx.y;
    if (p >= N) return;
    const long i = (long)t * N + p;
    const float dx = def[i*3], dy = def[i*3+1], dz = def[i*3+2];
    float fx, fy, fz;
    int3 b = base_cell(xs[i*3], xs[i*3+1], xs[i*3+2], fx, fy, fz);
    float wx[3], wy[3], wz[3];
    wx[0] = 0.5f*(1.5f-fx)*(1.5f-fx); wx[1] = 0.75f-(fx-1.f)*(fx-1.f); wx[2] = 0.5f*(fx-0.5f)*(fx-0.5f);
    wy[0] = 0.5f*(1.5f-fy)*(1.5f-fy); wy[1] = 0.75f-(fy-1.f)*(fy-1.f); wy[2] = 0.5f*(fy-0.5f)*(fy-0.5f);
    wz[0] = 0.5f*(1.5f-fz)*(1.5f-fz); wz[1] = 0.75f-(fz-1.f)*(fz-1.f); wz[2] = 0.5f*(fz-0.5f)*(fz-0.5f);
    const long tbase = (long)t * G * G * G;
    #pragma unroll
    for (int ii = 0; ii < 3; ++ii) {
        const long xoff = tbase + (long)(b.x + ii) * (G * G);
        #pragma unroll
        for (int jj = 0; jj < 3; ++jj) {
            const float wij = wx[ii] * wy[jj];
            const long yoff = xoff + (long)(b.y + jj) * G;
            #pragma unroll
            for (int kk = 0; kk < 3; ++kk) {
                const float w = wij * wz[kk];
                const long idx = yoff + (b.z + kk);
                atomicAdd(&grids[idx], w);
                atomicAdd(&gdef[idx*3+0], w * dx);
                atomicAdd(&gdef[idx*3+1], w * dy);
                atomicAdd(&gdef[idx*3+2], w * dz);
            }
        }
    }
}

extern "C" void kernel_launch(void* const* d_in, const int* in_sizes, int n_in,
                              void* d_out, int out_size, void* d_ws, size_t ws_size,
                              hipStream_t stream)
{
    const float* xs  = (const float*)d_in[0];
    const float* def = (const float*)d_in[1];
    float* out = (float*)d_out;

    const long Gcells = (long)CELLS;
    const int  T = (int)(out_size / (Gcells * 4));
    const int  N = in_sizes[0] / (3 * T);

    float* grids = out;
    float* gdef  = out + (long)T * Gcells;

    const size_t szA    = (size_t)T * N * sizeof(float4);
    const size_t szB    = (size_t)T * N * sizeof(float2);
    const size_t szArr  = (size_t)T * CELLS * sizeof(int);   // 64 MB
    const size_t szSums = (size_t)T * 512 * sizeof(int);
    const size_t need_full = szA + szB + szArr + szSums;

    if (ws_size >= need_full) {
        char* ws = (char*)d_ws;
        float4* sA   = (float4*)ws;  ws += szA;
        float2* sB   = (float2*)ws;  ws += szB;
        int*    arr  = (int*)ws;     ws += szArr;
        int*    sums = (int*)ws;

        hipMemsetAsync(arr, 0, szArr, stream);

        dim3 pgrid((N + 255) / 256, T);
        cell_hist    <<<pgrid, dim3(256), 0, stream>>>(xs, arr, N);
        scan1        <<<dim3(512, T), dim3(256), 0, stream>>>(arr, sums);
        scan2        <<<dim3(T), dim3(256), 0, stream>>>(sums);
        scan3        <<<dim3(CELLS / 1024, T), dim3(256), 0, stream>>>(arr, sums);
        scatter_cells<<<pgrid, dim3(256), 0, stream>>>(xs, def, arr, sA, sB, N);
        gather_cells <<<dim3(CELLS / 256, T), dim3(256), 0, stream>>>(sA, sB, arr,
                                                                      grids, gdef, N);
        return;
    }

    const size_t szInt = (size_t)T * NBINS * sizeof(int);
    const size_t need_tiled = szA + szB + 3 * szInt;

    if (ws_size >= need_tiled) {
        char* ws = (char*)d_ws;
        float4* sA       = (float4*)ws;  ws += szA;
        float2* sB       = (float2*)ws;  ws += szB;
        int*    hist     = (int*)ws;     ws += szInt;
        int*    cursor   = (int*)ws;     ws += szInt;
        int*    binstart = (int*)ws;

        hipMemsetAsync(hist, 0, szInt, stream);

        dim3 pgrid((N + 255) / 256, T);
        hist_kernel   <<<pgrid, dim3(256), 0, stream>>>(xs, hist, N);
        scan_kernel   <<<dim3(T), dim3(256), 0, stream>>>(hist, binstart, cursor);
        scatter_kernel<<<pgrid, dim3(256), 0, stream>>>(xs, def, cursor, sA, sB, N);
        p2g_tiled     <<<dim3(NBINS, T), dim3(128), 0, stream>>>(sA, sB, binstart, hist,
                                                                 grids, gdef, N);
        return;
    }

    hipMemsetAsync(d_out, 0, (size_t)out_size * sizeof(float), stream);
    dim3 grid((N + 255) / 256, T);
    p2g_direct<<<grid, dim3(256), 0, stream>>>(xs, def, grids, gdef, N);
}